// Round 9
// baseline (354.368 us; speedup 1.0000x reference)
//
#include <hip/hip_runtime.h>
#include <math.h>

#define BS   8
#define CIN  512
#define HC_  64
#define C2   256
#define NPIX 4096
#define WAO  384
#define TK   32           // KV tile size in k_attn
#define NT   (NPIX / TK)  // 128 KV steps

typedef __attribute__((ext_vector_type(8))) short short8;
typedef __attribute__((ext_vector_type(4))) float f32x4;

__device__ __forceinline__ ushort f2bf(float f) {
    union { float f; unsigned int u; } v; v.f = f;
    return (ushort)((v.u + 0x7FFFu + ((v.u >> 16) & 1u)) >> 16);
}

#define MFMA16(a, b, c) __builtin_amdgcn_mfma_f32_16x16x32_bf16((a), (b), (c), 0, 0, 0)

// async global->LDS, 16B per lane; LDS dest = base + lane*16 (wave-uniform base)
__device__ __forceinline__ void gl_lds16(const ushort* g, ushort* l) {
    __builtin_amdgcn_global_load_lds(
        (const __attribute__((address_space(1))) unsigned int*)g,
        (__attribute__((address_space(3))) unsigned int*)l, 16, 0, 0);
}

// ---------------------------------------------------------------------------
// Kernel W: convert Wa (384x512) and Wo (512x256) fp32 -> bf16 once.
// ---------------------------------------------------------------------------
__global__ __launch_bounds__(256) void k_cvt_w(
    const float* __restrict__ Wa, const float* __restrict__ Wo,
    ushort* __restrict__ wab, ushort* __restrict__ wob)
{
    const int i = (blockIdx.x * 256 + threadIdx.x) * 4;
    const int na = WAO * CIN;
    if (i < na) {
        const float4 v = *(const float4*)&Wa[i];
        ushort4 o; o.x = f2bf(v.x); o.y = f2bf(v.y); o.z = f2bf(v.z); o.w = f2bf(v.w);
        *(ushort4*)&wab[i] = o;
    } else {
        const int j = i - na;
        if (j < CIN * C2) {
            const float4 v = *(const float4*)&Wo[j];
            ushort4 o; o.x = f2bf(v.x); o.y = f2bf(v.y); o.z = f2bf(v.z); o.w = f2bf(v.w);
            *(ushort4*)&wob[j] = o;
        }
    }
}

// ---------------------------------------------------------------------------
// Kernel A (r4 version): w = Wa @ inputs, MFMA bf16, 3 o-tile blocks.
// Writes qt[b][n][64], kt[b][m][64] (transposed), vb[b][c][m] (natural).
// ---------------------------------------------------------------------------
__global__ __launch_bounds__(256) void k_proj_a(
    const float* __restrict__ inp, const ushort* __restrict__ wab,
    ushort* __restrict__ qt, ushort* __restrict__ kt, ushort* __restrict__ vb)
{
    __shared__ __align__(16) ushort it[64][40];
    const int b  = blockIdx.z;
    const int o0 = blockIdx.y * 128;
    const int n0 = blockIdx.x * 64;
    const int t    = threadIdx.x;
    const int wave = t >> 6, lane = t & 63;
    const int ln   = lane & 15, gr = lane >> 4;
    const int wn   = wave * 16;

    f32x4 acc[8];
#pragma unroll
    for (int i = 0; i < 8; ++i) acc[i] = (f32x4){0.f, 0.f, 0.f, 0.f};

    const int sc = t >> 4;
    const int sn = (t & 15) * 4;

    for (int ks = 0; ks < 16; ++ks) {
        const int c0 = ks * 32;
        __syncthreads();
#pragma unroll
        for (int q = 0; q < 2; ++q) {
            const int c = sc + 16 * q;
            const float4 v = *(const float4*)&inp[((size_t)b * CIN + c0 + c) * NPIX + n0 + sn];
            it[sn + 0][c] = f2bf(v.x); it[sn + 1][c] = f2bf(v.y);
            it[sn + 2][c] = f2bf(v.z); it[sn + 3][c] = f2bf(v.w);
        }
        __syncthreads();
        const short8 bf = *(const short8*)&it[wn + ln][gr * 8];
#pragma unroll
        for (int ot = 0; ot < 8; ++ot) {
            const int row = o0 + ot * 16 + ln;
            const short8 af = *(const short8*)&wab[(size_t)row * CIN + c0 + gr * 8];
            acc[ot] = MFMA16(af, bf, acc[ot]);
        }
    }

    const int n = n0 + wn + ln;
    if (o0 == 0) {
#pragma unroll
        for (int ot = 0; ot < 8; ++ot) {
            const ushort b0 = f2bf(acc[ot][0]), b1 = f2bf(acc[ot][1]);
            const ushort b2 = f2bf(acc[ot][2]), b3 = f2bf(acc[ot][3]);
            uint2 pk;
            pk.x = (unsigned int)b0 | ((unsigned int)b1 << 16);
            pk.y = (unsigned int)b2 | ((unsigned int)b3 << 16);
            ushort* base = (ot < 4) ? qt : kt;
            const int c4 = (ot & 3) * 16 + 4 * gr;
            *(uint2*)&base[((size_t)b * NPIX + n) * 64 + c4] = pk;
        }
    } else {
#pragma unroll
        for (int ot = 0; ot < 8; ++ot) {
            const int cb = o0 - 128 + ot * 16 + 4 * gr;
#pragma unroll
            for (int r = 0; r < 4; ++r)
                vb[((size_t)b * C2 + cb + r) * NPIX + n] = f2bf(acc[ot][r]);
        }
    }
}

// ---------------------------------------------------------------------------
// Kernel B: flash attention, bf16 MFMA. Pair-wave PV split (zero bank
// conflicts, 15 KB LDS/wave-step) + counted vmcnt pipeline (never drains
// to 0 in steady state):
//   body t = { stage_k(t+2); QK(t); softmax(t); lgkmcnt(0); vmcnt(1);
//              barrier; stage_v(t+1); partner-rescale; PV(t) }.
// K ring-3 staged 2 ahead (so only the oldest K + this V must land by the
// barrier -> vmcnt(1)); V ring-2 staged post-barrier (a full body of cover).
// P/resc/fl double-buffered so ONE barrier/step suffices.
// grid 512, b = bid&7 (one batch per XCD L2). Block = 4 waves x 16 q-rows;
// PV: wave covers its pair's 32 rows x a 128-col half.
// LDS: K 12K + V 32K + P 9K + stats ~0.8K = 54 KB -> 2 blocks/CU.
// ---------------------------------------------------------------------------
__global__ __launch_bounds__(256, 2) void k_attn(
    const ushort* __restrict__ qt, const ushort* __restrict__ kt,
    const ushort* __restrict__ vb, ushort* __restrict__ yt)
{
    __shared__ __align__(16) ushort ks[3][TK][64];    // [m][c], slot ^= (m&7)
    __shared__ __align__(16) ushort vs[2][C2][TK];    // [c][m], slot ^= ((c>>1)&3)
    __shared__ __align__(16) ushort ps[2][64][36];    // shared P [q][m], 72B stride
    __shared__ float resc_s[2][64];
    __shared__ float lsum_s[64];
    __shared__ int   fl[2][4];

    const int bid = blockIdx.x;
    const int b   = bid & 7;
    const int n0  = (bid >> 3) * 64;
    const int t    = threadIdx.x;
    const int wave = t >> 6, lane = t & 63;
    const int ln   = lane & 15, gr = lane >> 4;
    const int pr   = wave >> 1;        // pair index (rows 32*pr..32*pr+32)
    const int hf   = wave & 1;         // c-half (cols 128*hf..+128)

    const ushort* ktb = kt + (size_t)b * NPIX * 64;
    const ushort* vbb = vb + (size_t)b * C2 * NPIX;

    const int qrow = n0 + wave * 16 + ln;
    const short8 qf0 = *(const short8*)&qt[((size_t)b * NPIX + qrow) * 64 + gr * 8];
    const short8 qf1 = *(const short8*)&qt[((size_t)b * NPIX + qrow) * 64 + 32 + gr * 8];
    asm volatile("s_waitcnt vmcnt(0)" ::: "memory");   // exact vmcnt accounting
    __builtin_amdgcn_sched_barrier(0);

    // swizzled read offsets (ushort units)
    const int ksl0 = ((gr ^ (ln & 7)) << 3);
    const int ksl1 = (((4 + gr) ^ (ln & 7)) << 3);
    const int vsl  = ((gr ^ ((ln >> 1) & 3)) << 3);
    // staging lane roles (source pre-swizzled; LDS dest linear)
    const int krow = lane >> 3, kslot = (lane & 7) ^ krow;              // 8 m-rows
    const int vrow = lane >> 2, vslot = (lane & 3) ^ ((vrow >> 1) & 3); // 16 c-rows

    auto stage_k = [&](int buf, int tile) {
        const int m0 = tile * TK;
        gl_lds16(&ktb[(size_t)(m0 + 8 * wave + krow) * 64 + kslot * 8],
                 &ks[buf][8 * wave][0]);
    };
    auto stage_v = [&](int buf, int tile) {
        const int m0 = tile * TK;
#pragma unroll
        for (int jj = 0; jj < 4; ++jj) {
            const int r0 = 64 * wave + 16 * jj;
            gl_lds16(&vbb[(size_t)(r0 + vrow) * NPIX + m0 + vslot * 8],
                     &vs[buf][r0][0]);
        }
    };

    f32x4 y0[8], y1[8];
#pragma unroll
    for (int i = 0; i < 8; ++i) {
        y0[i] = (f32x4){0.f, 0.f, 0.f, 0.f};
        y1[i] = (f32x4){0.f, 0.f, 0.f, 0.f};
    }
    float mrun = -INFINITY, lrun = 0.f;
    const f32x4 zero = {0.f, 0.f, 0.f, 0.f};

    // prologue: K0, V0, K1 staged and drained once; loop never drains to 0.
    stage_k(0, 0);
    stage_v(0, 0);
    stage_k(1, 1);
    asm volatile("s_waitcnt vmcnt(0)" ::: "memory");
    __builtin_amdgcn_s_barrier();
    __builtin_amdgcn_sched_barrier(0);

    int kcur = 0;   // ks ring index of tile tt
    for (int tt = 0; tt < NT; ++tt) {
        const int pb = tt & 1;
        if (tt + 2 < NT) { int kp = kcur + 2; if (kp >= 3) kp -= 3; stage_k(kp, tt + 2); }

        // ---- S^T = K Q (own 16 rows): lane holds S[m=mt*16+4gr+r][q=16w+ln] ----
        f32x4 s[2];
#pragma unroll
        for (int mt = 0; mt < 2; ++mt) {
            const ushort* kp = &ks[kcur][mt * 16 + ln][0];
            const short8 kf0 = *(const short8*)(kp + ksl0);
            const short8 kf1 = *(const short8*)(kp + ksl1);
            s[mt] = MFMA16(kf1, qf1, MFMA16(kf0, qf0, zero));
        }
        // ---- online softmax, defer-max THR=8 ----
        float tm = fmaxf(fmaxf(fmaxf(s[0][0], s[0][1]), fmaxf(s[0][2], s[0][3])),
                         fmaxf(fmaxf(s[1][0], s[1][1]), fmaxf(s[1][2], s[1][3])));
        tm = fmaxf(tm, __shfl_xor(tm, 16));
        tm = fmaxf(tm, __shfl_xor(tm, 32));
        float rsc = 1.f;
        int flag = 0;
        if (__any(tm > mrun + 8.f)) {
            const float mnew = fmaxf(mrun, tm);
            rsc  = __expf(mrun - mnew);
            mrun = mnew;
            lrun *= rsc;
            flag = 1;
        }
        if (lane == 0) fl[pb][wave] = flag;
        if (gr == 0)   resc_s[pb][wave * 16 + ln] = rsc;
        const float p0 = __expf(s[0][0] - mrun), p1 = __expf(s[0][1] - mrun);
        const float p2 = __expf(s[0][2] - mrun), p3 = __expf(s[0][3] - mrun);
        const float p4 = __expf(s[1][0] - mrun), p5 = __expf(s[1][1] - mrun);
        const float p6 = __expf(s[1][2] - mrun), p7 = __expf(s[1][3] - mrun);
        uint2 w0, w1;
        w0.x = (unsigned int)f2bf(p0) | ((unsigned int)f2bf(p1) << 16);
        w0.y = (unsigned int)f2bf(p2) | ((unsigned int)f2bf(p3) << 16);
        w1.x = (unsigned int)f2bf(p4) | ((unsigned int)f2bf(p5) << 16);
        w1.y = (unsigned int)f2bf(p6) | ((unsigned int)f2bf(p7) << 16);
        *(uint2*)&ps[pb][wave * 16 + ln][4 * gr]      = w0;
        *(uint2*)&ps[pb][wave * 16 + ln][16 + 4 * gr] = w1;
        float rsum = (p0 + p1) + (p2 + p3) + ((p4 + p5) + (p6 + p7));
        rsum += __shfl_xor(rsum, 16);
        rsum += __shfl_xor(rsum, 32);
        lrun += rsum;

        // publish before barrier: P writes (lgkm) + oldest K + this V (vm).
        asm volatile("s_waitcnt lgkmcnt(0)" ::: "memory");
        if (tt + 2 < NT) { asm volatile("s_waitcnt vmcnt(1)" ::: "memory"); }
        else             { asm volatile("s_waitcnt vmcnt(0)" ::: "memory"); }
        __builtin_amdgcn_s_barrier();
        __builtin_amdgcn_sched_barrier(0);

        if (tt + 1 < NT) stage_v(pb ^ 1, tt + 1);   // ~full body of cover

        // ---- partner rescale (rare) ----
        const int f0 = fl[pb][2 * pr], f1 = fl[pb][2 * pr + 1];
        if (f0) {
            const float4 rs = *(const float4*)&resc_s[pb][32 * pr + 4 * gr];
#pragma unroll
            for (int ct = 0; ct < 8; ++ct) {
                y0[ct][0] *= rs.x; y0[ct][1] *= rs.y;
                y0[ct][2] *= rs.z; y0[ct][3] *= rs.w;
            }
        }
        if (f1) {
            const float4 rs = *(const float4*)&resc_s[pb][32 * pr + 16 + 4 * gr];
#pragma unroll
            for (int ct = 0; ct < 8; ++ct) {
                y1[ct][0] *= rs.x; y1[ct][1] *= rs.y;
                y1[ct][2] *= rs.z; y1[ct][3] *= rs.w;
            }
        }
        // ---- PV: pair's 32 rows x this wave's 128-col half ----
        const short8 pa0 = *(const short8*)&ps[pb][32 * pr + ln][gr * 8];
        const short8 pa1 = *(const short8*)&ps[pb][32 * pr + 16 + ln][gr * 8];
        const ushort* vbase = &vs[pb][128 * hf][0];
        __builtin_amdgcn_s_setprio(1);
#pragma unroll
        for (int ct = 0; ct < 8; ++ct) {
            const short8 vf = *(const short8*)(vbase + (ct * 16 + ln) * TK + vsl);
            y0[ct] = MFMA16(pa0, vf, y0[ct]);
            y1[ct] = MFMA16(pa1, vf, y1[ct]);
        }
        __builtin_amdgcn_s_setprio(0);
        __builtin_amdgcn_sched_barrier(0);

        kcur = kcur + 1; if (kcur >= 3) kcur -= 3;
    }

    // ---- epilogue: exchange l, normalize, write yt[b][n][c] bf16 ----
    if (gr == 0) lsum_s[wave * 16 + ln] = lrun;
    __syncthreads();
    const float4 ls0 = *(const float4*)&lsum_s[32 * pr + 4 * gr];
    const float4 ls1 = *(const float4*)&lsum_s[32 * pr + 16 + 4 * gr];
    const float a0 = 1.f / ls0.x, a1 = 1.f / ls0.y, a2 = 1.f / ls0.z, a3 = 1.f / ls0.w;
    const float b0 = 1.f / ls1.x, b1 = 1.f / ls1.y, b2 = 1.f / ls1.z, b3 = 1.f / ls1.w;
    const int nb0 = n0 + 32 * pr + 4 * gr;
    const int nb1 = nb0 + 16;
#pragma unroll
    for (int ct = 0; ct < 8; ++ct) {
        const int c = 128 * hf + ct * 16 + ln;
        yt[((size_t)b * NPIX + nb0 + 0) * C2 + c] = f2bf(y0[ct][0] * a0);
        yt[((size_t)b * NPIX + nb0 + 1) * C2 + c] = f2bf(y0[ct][1] * a1);
        yt[((size_t)b * NPIX + nb0 + 2) * C2 + c] = f2bf(y0[ct][2] * a2);
        yt[((size_t)b * NPIX + nb0 + 3) * C2 + c] = f2bf(y0[ct][3] * a3);
        yt[((size_t)b * NPIX + nb1 + 0) * C2 + c] = f2bf(y1[ct][0] * b0);
        yt[((size_t)b * NPIX + nb1 + 1) * C2 + c] = f2bf(y1[ct][1] * b1);
        yt[((size_t)b * NPIX + nb1 + 2) * C2 + c] = f2bf(y1[ct][2] * b2);
        yt[((size_t)b * NPIX + nb1 + 3) * C2 + c] = f2bf(y1[ct][3] * b3);
    }
}

// ---------------------------------------------------------------------------
// Kernel C (r4 version): out = gamma * (Wo @ y) + inputs, MFMA bf16, no LDS.
// ---------------------------------------------------------------------------
__global__ __launch_bounds__(256) void k_proj_o(
    const ushort* __restrict__ yt, const ushort* __restrict__ wob,
    const float* __restrict__ inp, const float* __restrict__ gamma,
    float* __restrict__ out)
{
    const int b  = blockIdx.z;
    const int j0 = blockIdx.y * 128;
    const int n0 = blockIdx.x * 64;
    const int t    = threadIdx.x;
    const int wave = t >> 6, lane = t & 63;
    const int ln   = lane & 15, gr = lane >> 4;
    const int n = n0 + wave * 16 + ln;

    f32x4 acc[8];
#pragma unroll
    for (int i = 0; i < 8; ++i) acc[i] = (f32x4){0.f, 0.f, 0.f, 0.f};

#pragma unroll
    for (int ksi = 0; ksi < 8; ++ksi) {
        const int c0 = ksi * 32;
        const short8 bf = *(const short8*)&yt[((size_t)b * NPIX + n) * C2 + c0 + gr * 8];
#pragma unroll
        for (int jt = 0; jt < 8; ++jt) {
            const int row = j0 + jt * 16 + ln;
            const short8 af = *(const short8*)&wob[(size_t)row * C2 + c0 + gr * 8];
            acc[jt] = MFMA16(af, bf, acc[jt]);
        }
    }
    const float g = gamma[0];
#pragma unroll
    for (int jt = 0; jt < 8; ++jt) {
#pragma unroll
        for (int r = 0; r < 4; ++r) {
            const int j = j0 + jt * 16 + 4 * gr + r;
            const size_t idx = ((size_t)b * CIN + j) * NPIX + n;
            out[idx] = fmaf(g, acc[jt][r], inp[idx]);
        }
    }
}

extern "C" void kernel_launch(void* const* d_in, const int* in_sizes, int n_in,
                              void* d_out, int out_size, void* d_ws, size_t ws_size,
                              hipStream_t stream) {
    const float* inputs = (const float*)d_in[0];
    const float* Wa     = (const float*)d_in[1];
    const float* Wo     = (const float*)d_in[2];
    const float* gamma  = (const float*)d_in[3];
    float* out = (float*)d_out;

    const size_t qt_e  = (size_t)BS * NPIX * 64;
    const size_t kt_e  = (size_t)BS * NPIX * 64;
    const size_t vb_e  = (size_t)BS * C2 * NPIX;
    const size_t yt_e  = (size_t)BS * NPIX * C2;
    const size_t wab_e = (size_t)WAO * CIN;
    const size_t wob_e = (size_t)CIN * C2;

    ushort *qt, *kt, *vb, *yt, *wab, *wob;
    if (ws_size >= (qt_e + kt_e + vb_e + yt_e + wab_e + wob_e) * sizeof(ushort)) {
        qt  = (ushort*)d_ws;
        kt  = qt + qt_e;
        vb  = kt + kt_e;
        yt  = vb + vb_e;
        wab = yt + yt_e;
        wob = wab + wab_e;
    } else {
        vb  = (ushort*)d_out;
        qt  = (ushort*)d_ws;
        kt  = qt + qt_e;
        yt  = kt + kt_e;
        wab = yt + yt_e;
        wob = wab + wab_e;
    }

    k_cvt_w <<<dim3(320),      256, 0, stream>>>(Wa, Wo, wab, wob);
    k_proj_a<<<dim3(64, 3, 8), 256, 0, stream>>>(inputs, wab, qt, kt, vb);
    k_attn  <<<dim3(512),      256, 0, stream>>>(qt, kt, vb, yt);
    k_proj_o<<<dim3(64, 4, 8), 256, 0, stream>>>(yt, wob, inputs, gamma, out);
}

// Round 10
// 346.742 us; speedup vs baseline: 1.0220x; 1.0220x over previous
//
#include <hip/hip_runtime.h>
#include <math.h>

#define BS   8
#define CIN  512
#define HC_  64
#define C2   256
#define NPIX 4096
#define WAO  384
#define TK   32            // KV tile size in k_attn
#define NTH  64            // KV steps per half (2-way KV split)

typedef __attribute__((ext_vector_type(8))) short short8;
typedef __attribute__((ext_vector_type(4))) float f32x4;

__device__ __forceinline__ ushort f2bf(float f) {
    union { float f; unsigned int u; } v; v.f = f;
    return (ushort)((v.u + 0x7FFFu + ((v.u >> 16) & 1u)) >> 16);
}
__device__ __forceinline__ float bf2f(ushort u) {
    union { unsigned int u; float f; } v; v.u = ((unsigned int)u) << 16;
    return v.f;
}

#define MFMA16(a, b, c) __builtin_amdgcn_mfma_f32_16x16x32_bf16((a), (b), (c), 0, 0, 0)

// async global->LDS, 16B per lane; LDS dest = base + lane*16 (wave-uniform base)
__device__ __forceinline__ void gl_lds16(const ushort* g, ushort* l) {
    __builtin_amdgcn_global_load_lds(
        (const __attribute__((address_space(1))) unsigned int*)g,
        (__attribute__((address_space(3))) unsigned int*)l, 16, 0, 0);
}

// ---------------------------------------------------------------------------
// Kernel W: convert Wa (384x512) and Wo (512x256) fp32 -> bf16 once.
// ---------------------------------------------------------------------------
__global__ __launch_bounds__(256) void k_cvt_w(
    const float* __restrict__ Wa, const float* __restrict__ Wo,
    ushort* __restrict__ wab, ushort* __restrict__ wob)
{
    const int i = (blockIdx.x * 256 + threadIdx.x) * 4;
    const int na = WAO * CIN;
    if (i < na) {
        const float4 v = *(const float4*)&Wa[i];
        ushort4 o; o.x = f2bf(v.x); o.y = f2bf(v.y); o.z = f2bf(v.z); o.w = f2bf(v.w);
        *(ushort4*)&wab[i] = o;
    } else {
        const int j = i - na;
        if (j < CIN * C2) {
            const float4 v = *(const float4*)&Wo[j];
            ushort4 o; o.x = f2bf(v.x); o.y = f2bf(v.y); o.z = f2bf(v.z); o.w = f2bf(v.w);
            *(ushort4*)&wob[j] = o;
        }
    }
}

// ---------------------------------------------------------------------------
// Kernel A (r4 version): w = Wa @ inputs, MFMA bf16, 3 o-tile blocks.
// Writes qt[b][n][64], kt[b][m][64] (transposed), vb[b][c][m] (natural).
// ---------------------------------------------------------------------------
__global__ __launch_bounds__(256) void k_proj_a(
    const float* __restrict__ inp, const ushort* __restrict__ wab,
    ushort* __restrict__ qt, ushort* __restrict__ kt, ushort* __restrict__ vb)
{
    __shared__ __align__(16) ushort it[64][40];
    const int b  = blockIdx.z;
    const int o0 = blockIdx.y * 128;
    const int n0 = blockIdx.x * 64;
    const int t    = threadIdx.x;
    const int wave = t >> 6, lane = t & 63;
    const int ln   = lane & 15, gr = lane >> 4;
    const int wn   = wave * 16;

    f32x4 acc[8];
#pragma unroll
    for (int i = 0; i < 8; ++i) acc[i] = (f32x4){0.f, 0.f, 0.f, 0.f};

    const int sc = t >> 4;
    const int sn = (t & 15) * 4;

    for (int ks = 0; ks < 16; ++ks) {
        const int c0 = ks * 32;
        __syncthreads();
#pragma unroll
        for (int q = 0; q < 2; ++q) {
            const int c = sc + 16 * q;
            const float4 v = *(const float4*)&inp[((size_t)b * CIN + c0 + c) * NPIX + n0 + sn];
            it[sn + 0][c] = f2bf(v.x); it[sn + 1][c] = f2bf(v.y);
            it[sn + 2][c] = f2bf(v.z); it[sn + 3][c] = f2bf(v.w);
        }
        __syncthreads();
        const short8 bf = *(const short8*)&it[wn + ln][gr * 8];
#pragma unroll
        for (int ot = 0; ot < 8; ++ot) {
            const int row = o0 + ot * 16 + ln;
            const short8 af = *(const short8*)&wab[(size_t)row * CIN + c0 + gr * 8];
            acc[ot] = MFMA16(af, bf, acc[ot]);
        }
    }

    const int n = n0 + wn + ln;
    if (o0 == 0) {
#pragma unroll
        for (int ot = 0; ot < 8; ++ot) {
            const ushort b0 = f2bf(acc[ot][0]), b1 = f2bf(acc[ot][1]);
            const ushort b2 = f2bf(acc[ot][2]), b3 = f2bf(acc[ot][3]);
            uint2 pk;
            pk.x = (unsigned int)b0 | ((unsigned int)b1 << 16);
            pk.y = (unsigned int)b2 | ((unsigned int)b3 << 16);
            ushort* base = (ot < 4) ? qt : kt;
            const int c4 = (ot & 3) * 16 + 4 * gr;
            *(uint2*)&base[((size_t)b * NPIX + n) * 64 + c4] = pk;
        }
    } else {
#pragma unroll
        for (int ot = 0; ot < 8; ++ot) {
            const int cb = o0 - 128 + ot * 16 + 4 * gr;
#pragma unroll
            for (int r = 0; r < 4; ++r)
                vb[((size_t)b * C2 + cb + r) * NPIX + n] = f2bf(acc[ot][r]);
        }
    }
}

// ---------------------------------------------------------------------------
// Kernel B: flash attention (r4 structure) + 2-way KV split + V ring-2 +
// shuffle-light softmax.
// grid 1024: bid = (h<<9)|(qtile<<3)|b -> b = bid&7 keeps one batch per XCD
// L2; h = KV half. Block = 4 waves x 16 q-rows, 64 steps over its half.
// Per step t: { stage_v(t+1)[V ring-2]; stage_k(t+2)[K ring-3]; QK(t);
//   softmax(t) [max-reduce only in rare defer-max branch; lrun kept as
//   per-lane partial]; lgkmcnt(0); PV(t); vmcnt(1); barrier }.
// End-of-step vmcnt(1) drains V(t+1)+K(t+1), leaves K(t+2) in flight;
// barrier makes them cross-wave visible (r4's race-free discipline).
// Output: unnormalized Yu (bf16) + per-row (m,l) -> merged by k_merge.
// LDS: K 12K + V 32K + P 5K = 49 KB -> 3 blocks/CU; 1024 blocks fill it.
// ---------------------------------------------------------------------------
__global__ __launch_bounds__(256, 3) void k_attn(
    const ushort* __restrict__ qt, const ushort* __restrict__ kt,
    const ushort* __restrict__ vb, ushort* __restrict__ yp,
    float2* __restrict__ ml)
{
    __shared__ __align__(16) ushort ks[3][TK][64];    // [m][c], slot ^= (m&7)
    __shared__ __align__(16) ushort vs[2][C2][TK];    // [c][m], slot ^= ((c>>1)&3)
    __shared__ __align__(16) ushort ps[4][16][40];    // per-wave P [n][m]

    const int bid = blockIdx.x;
    const int b   = bid & 7;
    const int n0  = ((bid >> 3) & 63) * 64;
    const int h   = bid >> 9;
    const int mb  = h * (NPIX / 2);
    const int t    = threadIdx.x;
    const int wave = t >> 6, lane = t & 63;
    const int ln   = lane & 15, gr = lane >> 4;

    const ushort* ktb = kt + (size_t)b * NPIX * 64;
    const ushort* vbb = vb + (size_t)b * C2 * NPIX;

    const int qrow = n0 + wave * 16 + ln;
    const short8 qf0 = *(const short8*)&qt[((size_t)b * NPIX + qrow) * 64 + gr * 8];
    const short8 qf1 = *(const short8*)&qt[((size_t)b * NPIX + qrow) * 64 + 32 + gr * 8];
    asm volatile("s_waitcnt vmcnt(0)" ::: "memory");   // exact vmcnt accounting
    __builtin_amdgcn_sched_barrier(0);

    // swizzled read offsets (ushort units)
    const int ksl0 = ((gr ^ (ln & 7)) << 3);
    const int ksl1 = (((4 + gr) ^ (ln & 7)) << 3);
    const int vsl  = ((gr ^ ((ln >> 1) & 3)) << 3);
    // staging lane roles (source pre-swizzled; LDS dest linear)
    const int krow = lane >> 3, kslot = (lane & 7) ^ krow;              // 8 m-rows
    const int vrow = lane >> 2, vslot = (lane & 3) ^ ((vrow >> 1) & 3); // 16 c-rows

    auto stage_k = [&](int buf, int tile) {
        const int m0 = mb + tile * TK;
        gl_lds16(&ktb[(size_t)(m0 + 8 * wave + krow) * 64 + kslot * 8],
                 &ks[buf][8 * wave][0]);
    };
    auto stage_v = [&](int buf, int tile) {
        const int m0 = mb + tile * TK;
#pragma unroll
        for (int jj = 0; jj < 4; ++jj) {
            const int r0 = 64 * wave + 16 * jj;
            gl_lds16(&vbb[(size_t)(r0 + vrow) * NPIX + m0 + vslot * 8],
                     &vs[buf][r0][0]);
        }
    };

    f32x4 yacc[16];
#pragma unroll
    for (int i = 0; i < 16; ++i) yacc[i] = (f32x4){0.f, 0.f, 0.f, 0.f};
    float mrun = -INFINITY, lrun = 0.f;    // lrun: per-lane partial row sum
    const f32x4 zero = {0.f, 0.f, 0.f, 0.f};

    // prologue: K0,V0 landed everywhere; K1 in flight.
    stage_k(0, 0);
    stage_v(0, 0);
    asm volatile("s_waitcnt vmcnt(0)" ::: "memory");
    stage_k(1, 1);
    __builtin_amdgcn_s_barrier();
    __builtin_amdgcn_sched_barrier(0);

    int kcur = 0;
    for (int tt = 0; tt < NTH; ++tt) {
        if (tt + 1 < NTH) stage_v((tt + 1) & 1, tt + 1);
        if (tt + 2 < NTH) { int kp = kcur + 2; if (kp >= 3) kp -= 3; stage_k(kp, tt + 2); }

        // ---- S^T = K Q : lane (gr,ln) holds S[m=mt*16+4gr+r][q-row ln] ----
        f32x4 s[2];
#pragma unroll
        for (int mt = 0; mt < 2; ++mt) {
            const ushort* kp = &ks[kcur][mt * 16 + ln][0];
            const short8 kf0 = *(const short8*)(kp + ksl0);
            const short8 kf1 = *(const short8*)(kp + ksl1);
            s[mt] = MFMA16(kf1, qf1, MFMA16(kf0, qf0, zero));
        }
        // ---- online softmax, defer-max THR=8, shuffle-light ----
        const float tm = fmaxf(fmaxf(fmaxf(s[0][0], s[0][1]), fmaxf(s[0][2], s[0][3])),
                               fmaxf(fmaxf(s[1][0], s[1][1]), fmaxf(s[1][2], s[1][3])));
        if (__any(tm > mrun + 8.f)) {
            float tr = fmaxf(tm, __shfl_xor(tm, 16));
            tr = fmaxf(tr, __shfl_xor(tr, 32));
            const float mnew = fmaxf(mrun, tr);      // row-uniform
            const float rsc  = __expf(mrun - mnew);
            mrun = mnew;
            lrun *= rsc;
            const float r0 = __shfl(rsc, 4 * gr + 0);
            const float r1 = __shfl(rsc, 4 * gr + 1);
            const float r2 = __shfl(rsc, 4 * gr + 2);
            const float r3 = __shfl(rsc, 4 * gr + 3);
#pragma unroll
            for (int ct = 0; ct < 16; ++ct) {
                yacc[ct][0] *= r0; yacc[ct][1] *= r1;
                yacc[ct][2] *= r2; yacc[ct][3] *= r3;
            }
        }
        const float p0 = __expf(s[0][0] - mrun), p1 = __expf(s[0][1] - mrun);
        const float p2 = __expf(s[0][2] - mrun), p3 = __expf(s[0][3] - mrun);
        const float p4 = __expf(s[1][0] - mrun), p5 = __expf(s[1][1] - mrun);
        const float p6 = __expf(s[1][2] - mrun), p7 = __expf(s[1][3] - mrun);
        uint2 w0, w1;
        w0.x = (unsigned int)f2bf(p0) | ((unsigned int)f2bf(p1) << 16);
        w0.y = (unsigned int)f2bf(p2) | ((unsigned int)f2bf(p3) << 16);
        w1.x = (unsigned int)f2bf(p4) | ((unsigned int)f2bf(p5) << 16);
        w1.y = (unsigned int)f2bf(p6) | ((unsigned int)f2bf(p7) << 16);
        *(uint2*)&ps[wave][ln][4 * gr]      = w0;
        *(uint2*)&ps[wave][ln][16 + 4 * gr] = w1;
        lrun += (p0 + p1) + (p2 + p3) + ((p4 + p5) + (p6 + p7));   // partial

        asm volatile("s_waitcnt lgkmcnt(0)" ::: "memory");   // own P visible
        __builtin_amdgcn_sched_barrier(0);
        const short8 pf = *(const short8*)&ps[wave][ln][gr * 8];
        // ---- Y += P V^T  (16 n x 256 c per wave) ----
        const ushort* vbase = &vs[tt & 1][0][0];
        __builtin_amdgcn_s_setprio(1);
#pragma unroll
        for (int ct = 0; ct < 16; ++ct) {
            const short8 vf = *(const short8*)(vbase + (ct * 16 + ln) * TK + vsl);
            yacc[ct] = MFMA16(pf, vf, yacc[ct]);
        }
        __builtin_amdgcn_s_setprio(0);
        __builtin_amdgcn_sched_barrier(0);

        if (tt + 1 < NTH) {
            if (tt + 2 < NTH) { asm volatile("s_waitcnt vmcnt(1)" ::: "memory"); }
            else              { asm volatile("s_waitcnt vmcnt(0)" ::: "memory"); }
            __builtin_amdgcn_s_barrier();
            __builtin_amdgcn_sched_barrier(0);
        }
        kcur = kcur + 1; if (kcur >= 3) kcur -= 3;
    }

    // ---- epilogue: reduce partial lrun, write Yu (unnormalized) + (m,l) ----
    lrun += __shfl_xor(lrun, 16);
    lrun += __shfl_xor(lrun, 32);          // full row sum, uniform across gr
    ushort* ypb = yp + (size_t)h * BS * NPIX * C2;
#pragma unroll
    for (int ct = 0; ct < 16; ++ct) {
        const int c = ct * 16 + ln;
        const int nb = n0 + wave * 16 + 4 * gr;
        ypb[((size_t)b * NPIX + nb + 0) * C2 + c] = f2bf(yacc[ct][0]);
        ypb[((size_t)b * NPIX + nb + 1) * C2 + c] = f2bf(yacc[ct][1]);
        ypb[((size_t)b * NPIX + nb + 2) * C2 + c] = f2bf(yacc[ct][2]);
        ypb[((size_t)b * NPIX + nb + 3) * C2 + c] = f2bf(yacc[ct][3]);
    }
    if (gr == 0) {   // lane ln holds row (n0 + wave*16 + ln)'s m,l
        const int n = n0 + wave * 16 + ln;
        ml[((size_t)h * BS + b) * NPIX + n] = make_float2(mrun, lrun);
    }
}

// ---------------------------------------------------------------------------
// Kernel M: merge the two KV-half partials into yt[b][n][c] bf16.
// ---------------------------------------------------------------------------
__global__ __launch_bounds__(256) void k_merge(
    const ushort* __restrict__ yp, const float2* __restrict__ ml,
    ushort* __restrict__ yt)
{
    const int idx = blockIdx.x * 256 + threadIdx.x;   // BS*NPIX*C2/4 threads
    const int row = idx >> 6;                         // b*NPIX + n
    const int cq  = (idx & 63) * 4;
    const float2 m1 = ml[row];
    const float2 m2 = ml[(size_t)BS * NPIX + row];
    const float ms = fmaxf(m1.x, m2.x);
    const float e1 = __expf(m1.x - ms), e2 = __expf(m2.x - ms);
    const float inv = 1.f / (e1 * m1.y + e2 * m2.y);
    const float w1 = e1 * inv, w2 = e2 * inv;
    const size_t off = (size_t)row * C2 + cq;
    const uint2 q1 = *(const uint2*)&yp[off];
    const uint2 q2 = *(const uint2*)&yp[(size_t)BS * NPIX * C2 + off];
    uint2 o;
    o.x = (unsigned int)f2bf(w1 * bf2f((ushort)(q1.x & 0xffff)) +
                             w2 * bf2f((ushort)(q2.x & 0xffff)))
        | ((unsigned int)f2bf(w1 * bf2f((ushort)(q1.x >> 16)) +
                              w2 * bf2f((ushort)(q2.x >> 16))) << 16);
    o.y = (unsigned int)f2bf(w1 * bf2f((ushort)(q1.y & 0xffff)) +
                             w2 * bf2f((ushort)(q2.y & 0xffff)))
        | ((unsigned int)f2bf(w1 * bf2f((ushort)(q1.y >> 16)) +
                              w2 * bf2f((ushort)(q2.y >> 16))) << 16);
    *(uint2*)&yt[off] = o;
}

// ---------------------------------------------------------------------------
// Kernel C (r4 version): out = gamma * (Wo @ y) + inputs, MFMA bf16, no LDS.
// ---------------------------------------------------------------------------
__global__ __launch_bounds__(256) void k_proj_o(
    const ushort* __restrict__ yt, const ushort* __restrict__ wob,
    const float* __restrict__ inp, const float* __restrict__ gamma,
    float* __restrict__ out)
{
    const int b  = blockIdx.z;
    const int j0 = blockIdx.y * 128;
    const int n0 = blockIdx.x * 64;
    const int t    = threadIdx.x;
    const int wave = t >> 6, lane = t & 63;
    const int ln   = lane & 15, gr = lane >> 4;
    const int n = n0 + wave * 16 + ln;

    f32x4 acc[8];
#pragma unroll
    for (int i = 0; i < 8; ++i) acc[i] = (f32x4){0.f, 0.f, 0.f, 0.f};

#pragma unroll
    for (int ksi = 0; ksi < 8; ++ksi) {
        const int c0 = ksi * 32;
        const short8 bf = *(const short8*)&yt[((size_t)b * NPIX + n) * C2 + c0 + gr * 8];
#pragma unroll
        for (int jt = 0; jt < 8; ++jt) {
            const int row = j0 + jt * 16 + ln;
            const short8 af = *(const short8*)&wob[(size_t)row * C2 + c0 + gr * 8];
            acc[jt] = MFMA16(af, bf, acc[jt]);
        }
    }
    const float g = gamma[0];
#pragma unroll
    for (int jt = 0; jt < 8; ++jt) {
#pragma unroll
        for (int r = 0; r < 4; ++r) {
            const int j = j0 + jt * 16 + 4 * gr + r;
            const size_t idx = ((size_t)b * CIN + j) * NPIX + n;
            out[idx] = fmaf(g, acc[jt][r], inp[idx]);
        }
    }
}

extern "C" void kernel_launch(void* const* d_in, const int* in_sizes, int n_in,
                              void* d_out, int out_size, void* d_ws, size_t ws_size,
                              hipStream_t stream) {
    const float* inputs = (const float*)d_in[0];
    const float* Wa     = (const float*)d_in[1];
    const float* Wo     = (const float*)d_in[2];
    const float* gamma  = (const float*)d_in[3];
    float* out = (float*)d_out;

    const size_t qt_e  = (size_t)BS * NPIX * 64;     // 2M ushort
    const size_t kt_e  = (size_t)BS * NPIX * 64;     // 2M
    const size_t yt_e  = (size_t)BS * NPIX * C2;     // 8M
    const size_t vb_e  = (size_t)BS * C2 * NPIX;     // 8M
    const size_t yp_e  = 2 * vb_e;                   // 16M (two halves)
    const size_t wab_e = (size_t)WAO * CIN;
    const size_t wob_e = (size_t)CIN * C2;

    // d_ws (needs 24.7 MB): qt, kt, yt, wab, wob.
    ushort* qt  = (ushort*)d_ws;
    ushort* kt  = qt + qt_e;
    ushort* yt  = kt + kt_e;
    ushort* wab = yt + yt_e;
    ushort* wob = wab + wab_e;
    // d_out (67.1 MB fp32 buffer) hosts scratch fully consumed before
    // k_proj_o writes it: vb [0,16MB), yp [16,48MB), ml [48,48.5MB).
    ushort* vb = (ushort*)d_out;
    ushort* yp = vb + vb_e;
    float2* ml = (float2*)(yp + yp_e);

    k_cvt_w <<<dim3(320),      256, 0, stream>>>(Wa, Wo, wab, wob);
    k_proj_a<<<dim3(64, 3, 8), 256, 0, stream>>>(inputs, wab, qt, kt, vb);
    k_attn  <<<dim3(1024),     256, 0, stream>>>(qt, kt, vb, yp, ml);
    k_merge <<<dim3(8192),     256, 0, stream>>>(yp, ml, yt);
    k_proj_o<<<dim3(64, 4, 8), 256, 0, stream>>>(yt, wob, inputs, gamma, out);
}